// Round 1
// baseline (303.535 us; speedup 1.0000x reference)
//
#include <hip/hip_runtime.h>
#include <math.h>

#define Hn 6
#define Bn 512
#define Dn 2048
#define Cn 1000
#define TAUv 0.5f

// ---------------- batched fp32 GEMM: logits[h] = feats[h] @ W[h] + b[h] ----------------
// Tile: 64(M) x 64(N), K-tile 16, 256 threads, 4x4 acc per thread.
#define TM 64
#define TN 64
#define TK 16

__global__ __launch_bounds__(256) void gemm_logits_k(
    const float* __restrict__ feats, const float* __restrict__ Wt,
    const float* __restrict__ bias, float* __restrict__ logits)
{
  const int h  = blockIdx.z;
  const int m0 = blockIdx.y * TM;
  const int n0 = blockIdx.x * TN;
  const float* A  = feats + (size_t)h * Bn * Dn;   // [B][D] row-major
  const float* Bm = Wt    + (size_t)h * Dn * Cn;   // [D][C] row-major

  __shared__ float As[TK][TM];   // transposed A tile: As[k][m]
  __shared__ float Bs[TK][TN];   // Bs[k][n]

  const int t   = threadIdx.x;
  const int a_m = t >> 2;              // 0..63
  const int a_k = (t & 3) << 2;        // 0,4,8,12
  const int b_k = t >> 4;              // 0..15
  const int b_n = (t & 15) << 2;       // 0..60
  const int tx  = t & 15, ty = t >> 4;
  const int mm  = ty << 2, nn = tx << 2;

  float acc[4][4] = {{0.f,0.f,0.f,0.f},{0.f,0.f,0.f,0.f},{0.f,0.f,0.f,0.f},{0.f,0.f,0.f,0.f}};

  for (int k0 = 0; k0 < Dn; k0 += TK) {
    // global loads (B=512, D=2048 are multiples of tile dims; only N needs guarding)
    const float4 av = *(const float4*)(A + (size_t)(m0 + a_m) * Dn + k0 + a_k);
    float4 bv;
    const int bn_g = n0 + b_n;
    if (bn_g + 3 < Cn) {
      bv = *(const float4*)(Bm + (size_t)(k0 + b_k) * Cn + bn_g);
    } else {
      const float* src = Bm + (size_t)(k0 + b_k) * Cn;
      bv.x = (bn_g + 0 < Cn) ? src[bn_g + 0] : 0.f;
      bv.y = (bn_g + 1 < Cn) ? src[bn_g + 1] : 0.f;
      bv.z = (bn_g + 2 < Cn) ? src[bn_g + 2] : 0.f;
      bv.w = (bn_g + 3 < Cn) ? src[bn_g + 3] : 0.f;
    }
    __syncthreads();   // previous iteration's compute done before overwrite
    As[a_k + 0][a_m] = av.x;
    As[a_k + 1][a_m] = av.y;
    As[a_k + 2][a_m] = av.z;
    As[a_k + 3][a_m] = av.w;
    *(float4*)(&Bs[b_k][b_n]) = bv;
    __syncthreads();

#pragma unroll
    for (int k = 0; k < TK; ++k) {
      const float4 af = *(const float4*)(&As[k][mm]);
      const float4 bf = *(const float4*)(&Bs[k][nn]);
      acc[0][0] = fmaf(af.x, bf.x, acc[0][0]);
      acc[0][1] = fmaf(af.x, bf.y, acc[0][1]);
      acc[0][2] = fmaf(af.x, bf.z, acc[0][2]);
      acc[0][3] = fmaf(af.x, bf.w, acc[0][3]);
      acc[1][0] = fmaf(af.y, bf.x, acc[1][0]);
      acc[1][1] = fmaf(af.y, bf.y, acc[1][1]);
      acc[1][2] = fmaf(af.y, bf.z, acc[1][2]);
      acc[1][3] = fmaf(af.y, bf.w, acc[1][3]);
      acc[2][0] = fmaf(af.z, bf.x, acc[2][0]);
      acc[2][1] = fmaf(af.z, bf.y, acc[2][1]);
      acc[2][2] = fmaf(af.z, bf.z, acc[2][2]);
      acc[2][3] = fmaf(af.z, bf.w, acc[2][3]);
      acc[3][0] = fmaf(af.w, bf.x, acc[3][0]);
      acc[3][1] = fmaf(af.w, bf.y, acc[3][1]);
      acc[3][2] = fmaf(af.w, bf.z, acc[3][2]);
      acc[3][3] = fmaf(af.w, bf.w, acc[3][3]);
    }
  }

  // epilogue: + bias, store
  float bl[4];
#pragma unroll
  for (int j = 0; j < 4; ++j) {
    const int n = n0 + nn + j;
    bl[j] = (n < Cn) ? bias[(size_t)h * Cn + n] : 0.f;
  }
#pragma unroll
  for (int i = 0; i < 4; ++i) {
    const int m = m0 + mm + i;
#pragma unroll
    for (int j = 0; j < 4; ++j) {
      const int n = n0 + nn + j;
      if (n < Cn)
        logits[(size_t)h * Bn * Cn + (size_t)m * Cn + n] = acc[i][j] + bl[j];
    }
  }
}

// ---------------- per-(h,b) max-softmax confidence ----------------
__global__ __launch_bounds__(256) void conf_k(const float* __restrict__ logits,
                                              float* __restrict__ conf)
{
  const int hb = blockIdx.x;                  // 0..H*B-1
  const float* row = logits + (size_t)hb * Cn;
  const int t = threadIdx.x;

  float vmax = -3.4e38f;
  for (int c = t; c < Cn; c += 256) vmax = fmaxf(vmax, row[c]);
#pragma unroll
  for (int off = 32; off >= 1; off >>= 1) vmax = fmaxf(vmax, __shfl_down(vmax, off));
  __shared__ float red[4];
  if ((t & 63) == 0) red[t >> 6] = vmax;
  __syncthreads();
  const float m = fmaxf(fmaxf(red[0], red[1]), fmaxf(red[2], red[3]));

  float s = 0.f;
  for (int c = t; c < Cn; c += 256) s += expf(row[c] - m);
#pragma unroll
  for (int off = 32; off >= 1; off >>= 1) s += __shfl_down(s, off);
  __shared__ float red2[4];
  if ((t & 63) == 0) red2[t >> 6] = s;
  __syncthreads();
  if (t == 0) {
    const float st = red2[0] + red2[1] + red2[2] + red2[3];
    conf[hb] = 1.0f / st;   // exp(m - m)/sum = max softmax prob
  }
}

// ---------------- routing ----------------
__global__ __launch_bounds__(256) void route_k(const float* __restrict__ conf,
                                               float* __restrict__ out_exit,
                                               int* __restrict__ exidx)
{
  const int b = blockIdx.x * blockDim.x + threadIdx.x;
  if (b >= Bn) return;
  int first = -1;
  float bestc = -3.4e38f;
  int best = 0;
  for (int h = 0; h < Hn; ++h) {
    const float c = conf[h * Bn + b];
    if (first < 0 && c >= TAUv) first = h;
    if (c > bestc) { bestc = c; best = h; }   // strict > keeps first occurrence
  }
  const int ex = (first >= 0) ? first : best;
  exidx[b] = ex;
  out_exit[b] = (float)ex;
}

// ---------------- gather chosen rows + CE loss + correct flag ----------------
__global__ __launch_bounds__(256) void pick_k(
    const float* __restrict__ logits, const int* __restrict__ exidx,
    const int* __restrict__ y, float* __restrict__ out,
    float* __restrict__ lossv, float* __restrict__ corr)
{
  const int b = blockIdx.x;
  const int ex = exidx[b];
  const float* row = logits + ((size_t)ex * Bn + b) * Cn;
  const int t = threadIdx.x;

  float vmax = -3.4e38f; int imax = Cn;
  for (int c = t; c < Cn; c += 256) {
    const float v = row[c];
    out[(size_t)b * Cn + c] = v;
    if (v > vmax || (v == vmax && c < imax)) { vmax = v; imax = c; }
  }
#pragma unroll
  for (int off = 32; off >= 1; off >>= 1) {
    const float ov = __shfl_down(vmax, off);
    const int   oi = __shfl_down(imax, off);
    if (ov > vmax || (ov == vmax && oi < imax)) { vmax = ov; imax = oi; }
  }
  __shared__ float rm[4]; __shared__ int ri[4];
  if ((t & 63) == 0) { rm[t >> 6] = vmax; ri[t >> 6] = imax; }
  __syncthreads();
  __shared__ float gm; __shared__ int gi;
  if (t == 0) {
    float bm = rm[0]; int bi = ri[0];
    for (int w = 1; w < 4; ++w)
      if (rm[w] > bm || (rm[w] == bm && ri[w] < bi)) { bm = rm[w]; bi = ri[w]; }
    gm = bm; gi = bi;
  }
  __syncthreads();
  const float m = gm;

  float s = 0.f;
  for (int c = t; c < Cn; c += 256) s += expf(row[c] - m);
#pragma unroll
  for (int off = 32; off >= 1; off >>= 1) s += __shfl_down(s, off);
  __shared__ float rs[4];
  if ((t & 63) == 0) rs[t >> 6] = s;
  __syncthreads();
  if (t == 0) {
    const float st = rs[0] + rs[1] + rs[2] + rs[3];
    const int yt = y[b];
    const float lp = row[yt] - m - logf(st);
    lossv[b] = -lp;
    corr[b] = (gi == yt) ? 1.f : 0.f;
  }
}

// ---------------- final scalar reductions ----------------
__global__ __launch_bounds__(512) void finish_k(const float* __restrict__ lossv,
                                                const float* __restrict__ corr,
                                                float* __restrict__ out)
{
  const int t = threadIdx.x;   // 512 threads, one per sample
  float l = lossv[t], c = corr[t];
#pragma unroll
  for (int off = 32; off >= 1; off >>= 1) { l += __shfl_down(l, off); c += __shfl_down(c, off); }
  __shared__ float rl[8], rc[8];
  if ((t & 63) == 0) { rl[t >> 6] = l; rc[t >> 6] = c; }
  __syncthreads();
  if (t == 0) {
    float ls = 0.f, cs = 0.f;
    for (int w = 0; w < 8; ++w) { ls += rl[w]; cs += rc[w]; }
    out[(size_t)Bn * Cn + Bn + 0] = ls / (float)Bn;
    out[(size_t)Bn * Cn + Bn + 1] = cs / (float)Bn;
  }
}

extern "C" void kernel_launch(void* const* d_in, const int* in_sizes, int n_in,
                              void* d_out, int out_size, void* d_ws, size_t ws_size,
                              hipStream_t stream) {
  const float* feats = (const float*)d_in[0];   // [H,B,D]
  const float* W     = (const float*)d_in[1];   // [H,D,C]
  const float* bias  = (const float*)d_in[2];   // [H,C]
  const int*   y     = (const int*)d_in[3];     // [B]
  float* out = (float*)d_out;                   // [B*C | B | 1 | 1]

  float* logits = (float*)d_ws;                           // H*B*C
  float* conf   = logits + (size_t)Hn * Bn * Cn;          // H*B
  int*   exidx  = (int*)(conf + Hn * Bn);                 // B
  float* lossv  = (float*)(exidx + Bn);                   // B
  float* corr   = lossv + Bn;                             // B

  dim3 g1((Cn + TN - 1) / TN, Bn / TM, Hn);   // 16 x 8 x 6 = 768 blocks
  gemm_logits_k<<<g1, 256, 0, stream>>>(feats, W, bias, logits);
  conf_k<<<Hn * Bn, 256, 0, stream>>>(logits, conf);
  route_k<<<(Bn + 255) / 256, 256, 0, stream>>>(conf, out + (size_t)Bn * Cn, exidx);
  pick_k<<<Bn, 256, 0, stream>>>(logits, exidx, y, out, lossv, corr);
  finish_k<<<1, 512, 0, stream>>>(lossv, corr, out);
}